// Round 4
// baseline (703.173 us; speedup 1.0000x reference)
//
#include <hip/hip_runtime.h>

#define KK 8192
#define DD 64
#define NN 16384
#define DECAYF 0.99f
#define EPSF 1e-5f
#define BATCHF 32.0f
#define CSPLIT 32
#define CODES_PER_BLK (KK / CSPLIT)       // 256 codes -> 32 KB bf16 LDS tile
#define NCT (CODES_PER_BLK / 16)          // 16 MFMA code-tiles per block
#define TOKS_PER_WAVE 128                 // 8 subtiles of 16
#define NSUB 8
#define XMARGIN 2.0f                      // split-qualify margin (half-score)

using short8  = __attribute__((ext_vector_type(8))) short;
using floatx4 = __attribute__((ext_vector_type(4))) float;

// ---- helpers ----
__device__ __forceinline__ unsigned short f2bf(float f) {  // RNE bf16
  unsigned u = __float_as_uint(f);
  return (unsigned short)((u + 0x7FFFu + ((u >> 16) & 1u)) >> 16);
}
__device__ __forceinline__ unsigned ford(float f) {        // order-preserving f32->u32
  unsigned u = __float_as_uint(f);
  return (u & 0x80000000u) ? ~u : (u | 0x80000000u);
}
__device__ __forceinline__ float funord(unsigned u) {
  unsigned b = (u & 0x80000000u) ? (u ^ 0x80000000u) : ~u;
  return __uint_as_float(b);
}

// ---- init workspace: zero sums+counts, init minc ----
__global__ __launch_bounds__(256) void init_kernel(float4* __restrict__ sums4,
                                                   unsigned* __restrict__ minc) {
  int i = blockIdx.x * 256 + threadIdx.x;   // grid 520
  if (i < (KK * DD + KK) / 4) sums4[i] = make_float4(0.f, 0.f, 0.f, 0.f);
  if (i < NN) minc[i] = 0xFFFFFFFFu;
}

// ---- fp32 -> bf16 ----
__global__ __launch_bounds__(256) void conv_kernel(const float4* __restrict__ src,
                                                   uint2* __restrict__ dst, int n4) {
  int i = blockIdx.x * 256 + threadIdx.x;
  if (i >= n4) return;
  float4 v = src[i];
  uint2 o;
  o.x = (unsigned)f2bf(v.x) | ((unsigned)f2bf(v.y) << 16);
  o.y = (unsigned)f2bf(v.z) | ((unsigned)f2bf(v.w) << 16);
  dst[i] = o;
}

// ---- exact fp32 per-code squared norms ----
__global__ __launch_bounds__(256) void c2_kernel(const float* __restrict__ cb,
                                                 float* __restrict__ c2) {
  int k = blockIdx.x * 256 + threadIdx.x;
  const float4* r = (const float4*)(cb + (size_t)k * DD);
  float s = 0.f;
  #pragma unroll
  for (int i = 0; i < DD / 4; ++i) {
    float4 v = r[i];
    s = fmaf(v.x, v.x, s); s = fmaf(v.y, v.y, s);
    s = fmaf(v.z, v.z, s); s = fmaf(v.w, v.w, s);
  }
  c2[k] = s;
}

// ---- codebook transpose: cbT4[d*2048 + k4] = {cb[4k4..4k4+3][d]} ----
__global__ __launch_bounds__(256) void transpose_kernel(const float* __restrict__ cb,
                                                        float4* __restrict__ cbT4) {
  int i = blockIdx.x * 256 + threadIdx.x;   // grid 512 -> 131072
  int d = i >> 11, k4 = i & 2047;
  float4 v;
  v.x = cb[(size_t)(k4 * 4 + 0) * DD + d];
  v.y = cb[(size_t)(k4 * 4 + 1) * DD + d];
  v.z = cb[(size_t)(k4 * 4 + 2) * DD + d];
  v.w = cb[(size_t)(k4 * 4 + 3) * DD + d];
  cbT4[i] = v;
}

// ---- LDS staging: 256-code bf16 slice, XOR-swizzled 16B chunks ----
__device__ __forceinline__ void stage_tile(const float4* __restrict__ cbb4,
                                           const float* __restrict__ c2,
                                           int code0, float4* tile, float* c2s) {
  const int tid = threadIdx.x;
  #pragma unroll
  for (int it = 0; it < 8; ++it) {
    int C = it * 256 + tid;          // linear 16B chunk 0..2047
    int r = C >> 3, c = C & 7;
    tile[C] = cbb4[(size_t)(code0 + r) * 8 + (c ^ (r & 7))];
  }
  c2s[tid] = c2[code0 + tid];
}

// ---- pass 1: bf16 MFMA coarse half-score min; writes per-(token,split) min ----
__global__ __launch_bounds__(256, 2) void pass1_kernel(const unsigned short* __restrict__ xb,
                                                       const float4* __restrict__ cbb4,
                                                       const float* __restrict__ c2,
                                                       unsigned* __restrict__ minc,
                                                       float* __restrict__ splitmin) {
  __shared__ float4 tile[CODES_PER_BLK * 8];
  __shared__ float c2s[CODES_PER_BLK];
  const int lane = threadIdx.x & 63;
  const int wave = threadIdx.x >> 6;
  const int col = lane & 15, q = lane >> 4;
  const int tokbase = (blockIdx.x / CSPLIT) * 512 + wave * TOKS_PER_WAVE;
  const int split = blockIdx.x % CSPLIT;
  const int code0 = split * CODES_PER_BLK;

  stage_tile(cbb4, c2, code0, tile, c2s);

  short8 a[NSUB][2];
  #pragma unroll
  for (int s = 0; s < NSUB; ++s)
    #pragma unroll
    for (int kk = 0; kk < 2; ++kk)
      a[s][kk] = *(const short8*)(xb + (size_t)(tokbase + s * 16 + col) * DD + kk * 32 + q * 8);

  float mn[NSUB][4];
  #pragma unroll
  for (int s = 0; s < NSUB; ++s)
    #pragma unroll
    for (int r = 0; r < 4; ++r) mn[s][r] = 3.4e38f;

  __syncthreads();

  for (int ct = 0; ct < NCT; ++ct) {
    const int row = ct * 16 + col;
    const int rb = row * 8, rx = row & 7;
    short8 b0 = *(const short8*)&tile[rb + (q ^ rx)];
    short8 b1 = *(const short8*)&tile[rb + ((q + 4) ^ rx)];
    const float h = 0.5f * c2s[row];
    #pragma unroll
    for (int s = 0; s < NSUB; ++s) {
      floatx4 acc = {0.f, 0.f, 0.f, 0.f};
      acc = __builtin_amdgcn_mfma_f32_16x16x32_bf16(a[s][0], b0, acc, 0, 0, 0);
      acc = __builtin_amdgcn_mfma_f32_16x16x32_bf16(a[s][1], b1, acc, 0, 0, 0);
      #pragma unroll
      for (int r = 0; r < 4; ++r)
        mn[s][r] = fminf(mn[s][r], h - acc[r]);   // half-score = 0.5*c2 - dot
    }
  }

  #pragma unroll
  for (int off = 1; off < 16; off <<= 1)
    #pragma unroll
    for (int s = 0; s < NSUB; ++s)
      #pragma unroll
      for (int r = 0; r < 4; ++r)
        mn[s][r] = fminf(mn[s][r], __shfl_xor(mn[s][r], off, 64));

  if (col == 0) {
    #pragma unroll
    for (int s = 0; s < NSUB; ++s)
      #pragma unroll
      for (int r = 0; r < 4; ++r) {
        const int tok = tokbase + s * 16 + q * 4 + r;
        splitmin[(size_t)tok * CSPLIT + split] = mn[s][r];
        atomicMin(&minc[tok], ford(mn[s][r]));
      }
  }
}

// ---- exact pass: per token, scan only qualifying splits with fp32 ----
// wave = 1 token; lane owns 4 codes (via transposed codebook, coalesced).
// Fuses refine + tokfin: writes bestidx, quant row, counts, sums.
__global__ __launch_bounds__(256) void exact_kernel(const float* __restrict__ x,
                                                    const float4* __restrict__ cbT4,
                                                    const float4* __restrict__ c24,
                                                    const float* __restrict__ cb,
                                                    const unsigned* __restrict__ minc,
                                                    const float* __restrict__ splitmin,
                                                    unsigned* __restrict__ bestidx,
                                                    float* __restrict__ quant,
                                                    float* __restrict__ counts,
                                                    float* __restrict__ sums) {
  const int wv = threadIdx.x >> 6;
  const int lane = threadIdx.x & 63;
  const int tok = __builtin_amdgcn_readfirstlane(blockIdx.x * 4 + wv);

  // broadcast x row (uniform address)
  float4 xr[16];
  const float4* xp = (const float4*)(x + (size_t)tok * DD);
  #pragma unroll
  for (int i = 0; i < 16; ++i) xr[i] = xp[i];

  const float gmin = funord(minc[tok]);
  float sm = (lane < CSPLIT) ? splitmin[(size_t)tok * CSPLIT + lane] : 3.4e38f;
  unsigned long long mask = __ballot((lane < CSPLIT) && (sm <= gmin + XMARGIN));

  float bs = 3.4e38f;
  int bc = 0x7FFFFFFF;

  while (mask) {
    const int s = __builtin_ctzll(mask);   // ascending splits -> ascending codes
    mask &= mask - 1;
    const int k4 = s * 64 + lane;          // this lane's 4 codes: 4*k4 .. 4*k4+3
    float4 acc = {0.f, 0.f, 0.f, 0.f};
    #pragma unroll
    for (int d = 0; d < DD; ++d) {
      const float xd = ((const float*)xr)[d];       // constant idx after unroll
      const float4 cv = cbT4[(size_t)d * 2048 + k4]; // coalesced 1KB/wave
      acc.x = fmaf(xd, cv.x, acc.x);
      acc.y = fmaf(xd, cv.y, acc.y);
      acc.z = fmaf(xd, cv.z, acc.z);
      acc.w = fmaf(xd, cv.w, acc.w);
    }
    const float4 cc = c24[k4];
    const int cbase = k4 * 4;
    float sc;
    sc = fmaf(-2.f, acc.x, cc.x); if (sc < bs) { bs = sc; bc = cbase; }
    sc = fmaf(-2.f, acc.y, cc.y); if (sc < bs) { bs = sc; bc = cbase + 1; }
    sc = fmaf(-2.f, acc.z, cc.z); if (sc < bs) { bs = sc; bc = cbase + 2; }
    sc = fmaf(-2.f, acc.w, cc.w); if (sc < bs) { bs = sc; bc = cbase + 3; }
  }

  // 64-lane argmin reduce with lowest-index tie-break
  #pragma unroll
  for (int off = 32; off; off >>= 1) {
    float os = __shfl_xor(bs, off, 64);
    int oc = __shfl_xor(bc, off, 64);
    if (os < bs || (os == bs && oc < bc)) { bs = os; bc = oc; }
  }

  const int code = __builtin_amdgcn_readfirstlane(bc);
  quant[(size_t)tok * DD + lane] = cb[(size_t)code * DD + lane];
  atomicAdd(&sums[(size_t)code * DD + lane], x[(size_t)tok * DD + lane]);
  if (lane == 0) {
    bestidx[tok] = (unsigned)code;
    atomicAdd(&counts[code], 1.0f);
  }
}

// ---- one-hot fill: zeros + ones in a single 512 MiB pass ----
__global__ __launch_bounds__(256) void fill_kernel(const unsigned* __restrict__ bestidx,
                                                   float4* __restrict__ d4) {
  const size_t stride = (size_t)gridDim.x * 256;
  const size_t total = (size_t)NN * (KK / 4);
  for (size_t g = (size_t)blockIdx.x * 256 + threadIdx.x; g < total; g += stride) {
    const int n = (int)(g >> 11);          // 2048 float4 per row
    const int k0 = ((int)g & 2047) << 2;
    const int bi = (int)bestidx[n];        // broadcast within wave, L1-hit
    float4 v;
    v.x = (k0 == bi) ? 1.f : 0.f;
    v.y = (k0 + 1 == bi) ? 1.f : 0.f;
    v.z = (k0 + 2 == bi) ? 1.f : 0.f;
    v.w = (k0 + 3 == bi) ? 1.f : 0.f;
    d4[g] = v;
  }
}

// ---- EMA finalize ----
__global__ __launch_bounds__(256) void finalize_kernel(
    const float* __restrict__ ema_count, const float* __restrict__ ema_weight,
    const float* __restrict__ counts, const float* __restrict__ sums,
    float* __restrict__ out_count, float* __restrict__ out_weight,
    float* __restrict__ out_cb) {
  const int e4 = blockIdx.x * 256 + threadIdx.x;
  const int k = e4 >> 4;
  float nc = ema_count[k] * DECAYF + counts[k] * (1.f - DECAYF);
  nc = (nc + EPSF) / (BATCHF + (float)KK * EPSF) * BATCHF;
  const float4 ew = ((const float4*)ema_weight)[e4];
  const float4 s  = ((const float4*)sums)[e4];
  float4 nw;
  nw.x = ew.x * DECAYF + s.x * (1.f - DECAYF);
  nw.y = ew.y * DECAYF + s.y * (1.f - DECAYF);
  nw.z = ew.z * DECAYF + s.z * (1.f - DECAYF);
  nw.w = ew.w * DECAYF + s.w * (1.f - DECAYF);
  ((float4*)out_weight)[e4] = nw;
  float4 ncb = make_float4(nw.x / nc, nw.y / nc, nw.z / nc, nw.w / nc);
  ((float4*)out_cb)[e4] = ncb;
  if ((e4 & 15) == 0) out_count[k] = nc;
}

extern "C" void kernel_launch(void* const* d_in, const int* in_sizes, int n_in,
                              void* d_out, int out_size, void* d_ws, size_t ws_size,
                              hipStream_t stream) {
  const float* x  = (const float*)d_in[0];
  const float* cb = (const float*)d_in[1];
  const float* ema_count  = (const float*)d_in[2];
  const float* ema_weight = (const float*)d_in[3];

  float* out        = (float*)d_out;
  float* disc       = out;
  float* quant      = disc + (size_t)NN * KK;
  float* out_count  = quant + (size_t)NN * DD;
  float* out_weight = out_count + KK;
  float* out_cb     = out_weight + (size_t)KK * DD;

  float* ws = (float*)d_ws;
  float*    sums     = ws;                                   // 524288 f
  float*    counts   = sums + (size_t)KK * DD;               // 8192 f
  float*    c2       = counts + KK;                          // 8192 f
  unsigned* minc     = (unsigned*)(c2 + KK);                 // 16384 u32
  float*    splitmin = (float*)(minc + NN);                  // 524288 f (N x 32)
  unsigned* bestidx  = (unsigned*)(splitmin + (size_t)NN * CSPLIT);  // 16384 u32
  unsigned short* xb  = (unsigned short*)(bestidx + NN);     // 1M bf16
  unsigned short* cbb = xb + (size_t)NN * DD;                // 512K bf16
  float*    cbT      = (float*)(cbb + (size_t)KK * DD);      // 524288 f transposed

  init_kernel<<<520, 256, 0, stream>>>((float4*)sums, minc);
  conv_kernel<<<NN * DD / 4 / 256, 256, 0, stream>>>((const float4*)x, (uint2*)xb, NN * DD / 4);
  conv_kernel<<<KK * DD / 4 / 256, 256, 0, stream>>>((const float4*)cb, (uint2*)cbb, KK * DD / 4);
  c2_kernel<<<KK / 256, 256, 0, stream>>>(cb, c2);
  transpose_kernel<<<KK * DD / 4 / 256, 256, 0, stream>>>(cb, (float4*)cbT);
  pass1_kernel<<<(NN / 512) * CSPLIT, 256, 0, stream>>>(xb, (const float4*)cbb, c2, minc, splitmin);
  exact_kernel<<<NN / 4, 256, 0, stream>>>(x, (const float4*)cbT, (const float4*)c2, cb,
                                           minc, splitmin, bestidx, quant, counts, sums);
  fill_kernel<<<2048, 256, 0, stream>>>(bestidx, (float4*)disc);
  finalize_kernel<<<KK * DD / 4 / 256, 256, 0, stream>>>(
      ema_count, ema_weight, counts, sums, out_count, out_weight, out_cb);
}

// Round 6
// 652.648 us; speedup vs baseline: 1.0774x; 1.0774x over previous
//
#include <hip/hip_runtime.h>

#define KK 8192
#define DD 64
#define NN 16384
#define DECAYF 0.99f
#define EPSF 1e-5f
#define BATCHF 32.0f
#define CSPLIT 64
#define CODES_PER_BLK (KK / CSPLIT)       // 128 codes -> 16 KB bf16 LDS tile
#define NCT (CODES_PER_BLK / 16)          // 8 MFMA code-tiles per block
#define NSUB 8                            // 128 tokens per wave
#define XMARGIN 2.0f                      // split-qualify margin (half-score)

using short8  = __attribute__((ext_vector_type(8))) short;
using floatx4 = __attribute__((ext_vector_type(4))) float;

__device__ __forceinline__ unsigned short f2bf(float f) {  // RNE bf16
  unsigned u = __float_as_uint(f);
  return (unsigned short)((u + 0x7FFFu + ((u >> 16) & 1u)) >> 16);
}

// ---- x: fp32 -> bf16 ----
__global__ __launch_bounds__(256) void conv_kernel(const float4* __restrict__ src,
                                                   uint2* __restrict__ dst, int n4) {
  int i = blockIdx.x * 256 + threadIdx.x;
  if (i >= n4) return;
  float4 v = src[i];
  uint2 o;
  o.x = (unsigned)f2bf(v.x) | ((unsigned)f2bf(v.y) << 16);
  o.y = (unsigned)f2bf(v.z) | ((unsigned)f2bf(v.w) << 16);
  dst[i] = o;
}

// ---- codebook prep: bf16 conv + c2 + fp32 transpose, one pass ----
__global__ __launch_bounds__(256) void cbprep_kernel(const float* __restrict__ cb,
                                                     unsigned short* __restrict__ cbb,
                                                     float* __restrict__ c2,
                                                     float* __restrict__ cbT) {
  const int k = blockIdx.x * 256 + threadIdx.x;
  float4 row[16];
  const float4* rp = (const float4*)(cb + (size_t)k * DD);
  #pragma unroll
  for (int i = 0; i < 16; ++i) row[i] = rp[i];

  float s = 0.f;
  #pragma unroll
  for (int i = 0; i < 16; ++i) {
    s = fmaf(row[i].x, row[i].x, s); s = fmaf(row[i].y, row[i].y, s);
    s = fmaf(row[i].z, row[i].z, s); s = fmaf(row[i].w, row[i].w, s);
  }
  c2[k] = s;

  // row[i] (4 floats) -> bp[i] (one uint2 = 4 bf16). FIXED: was bp[i>>1].
  uint2* bp = (uint2*)(cbb + (size_t)k * DD);
  #pragma unroll
  for (int i = 0; i < 16; ++i) {
    uint2 o;
    o.x = (unsigned)f2bf(row[i].x) | ((unsigned)f2bf(row[i].y) << 16);
    o.y = (unsigned)f2bf(row[i].z) | ((unsigned)f2bf(row[i].w) << 16);
    bp[i] = o;
  }

  // transposed: cbT[d*KK + k], coalesced across the wave for each d
  #pragma unroll
  for (int i = 0; i < 16; ++i) {
    cbT[(size_t)(i * 4 + 0) * KK + k] = row[i].x;
    cbT[(size_t)(i * 4 + 1) * KK + k] = row[i].y;
    cbT[(size_t)(i * 4 + 2) * KK + k] = row[i].z;
    cbT[(size_t)(i * 4 + 3) * KK + k] = row[i].w;
  }
}

// ---- LDS staging: 128-code bf16 slice, XOR-swizzled 16B chunks ----
__device__ __forceinline__ void stage_tile(const float4* __restrict__ cbb4,
                                           const float* __restrict__ c2,
                                           int code0, float4* tile, float* c2h) {
  const int tid = threadIdx.x;
  #pragma unroll
  for (int it = 0; it < 4; ++it) {
    int C = it * 256 + tid;          // linear 16B chunk 0..1023
    int r = C >> 3, c = C & 7;
    tile[C] = cbb4[(size_t)(code0 + r) * 8 + (c ^ (r & 7))];
  }
  if (tid < CODES_PER_BLK) c2h[tid] = 0.5f * c2[code0 + tid];
}

// ---- pass 1: bf16 MFMA coarse half-score min per (token, split) ----
// acc initialized to -0.5*c2[code] (valid: all 4 C/D regs of a lane share
// the same code column n = lane&15), epilogue is a single fmax.
__global__ __launch_bounds__(256, 2) void pass1_kernel(const unsigned short* __restrict__ xb,
                                                       const float4* __restrict__ cbb4,
                                                       const float* __restrict__ c2,
                                                       float* __restrict__ splitmin) {
  __shared__ float4 tile[CODES_PER_BLK * 8];
  __shared__ float c2h[CODES_PER_BLK];
  const int lane = threadIdx.x & 63;
  const int wave = threadIdx.x >> 6;
  const int col = lane & 15, q = lane >> 4;
  const int tokbase = (blockIdx.x / CSPLIT) * 512 + wave * 128;
  const int split = blockIdx.x % CSPLIT;
  const int code0 = split * CODES_PER_BLK;

  stage_tile(cbb4, c2, code0, tile, c2h);

  short8 a[NSUB][2];
  #pragma unroll
  for (int s = 0; s < NSUB; ++s)
    #pragma unroll
    for (int kk = 0; kk < 2; ++kk)
      a[s][kk] = *(const short8*)(xb + (size_t)(tokbase + s * 16 + col) * DD + kk * 32 + q * 8);

  float mx[NSUB][4];
  #pragma unroll
  for (int s = 0; s < NSUB; ++s)
    #pragma unroll
    for (int r = 0; r < 4; ++r) mx[s][r] = -3.4e38f;

  __syncthreads();

  int row = col, rb = col * 8, rx = col & 7;
  short8 b0 = *(const short8*)&tile[rb + (q ^ rx)];
  short8 b1 = *(const short8*)&tile[rb + ((q + 4) ^ rx)];

  for (int ct = 0; ct < NCT; ++ct) {
    short8 nb0, nb1;
    if (ct + 1 < NCT) {                 // prefetch next B-frags
      int nrow = (ct + 1) * 16 + col, nrb = nrow * 8, nrx = nrow & 7;
      nb0 = *(const short8*)&tile[nrb + (q ^ nrx)];
      nb1 = *(const short8*)&tile[nrb + ((q + 4) ^ nrx)];
    }
    const float mh = -c2h[row];         // acc starts at -0.5*||c||^2
    #pragma unroll
    for (int s = 0; s < NSUB; ++s) {
      floatx4 acc = {mh, mh, mh, mh};
      acc = __builtin_amdgcn_mfma_f32_16x16x32_bf16(a[s][0], b0, acc, 0, 0, 0);
      acc = __builtin_amdgcn_mfma_f32_16x16x32_bf16(a[s][1], b1, acc, 0, 0, 0);
      #pragma unroll
      for (int r = 0; r < 4; ++r)
        mx[s][r] = fmaxf(mx[s][r], acc[r]);   // max(dot - 0.5c2) = -min half-score
    }
    b0 = nb0; b1 = nb1;
    row = (ct + 1) * 16 + col;
  }

  #pragma unroll
  for (int off = 1; off < 16; off <<= 1)
    #pragma unroll
    for (int s = 0; s < NSUB; ++s)
      #pragma unroll
      for (int r = 0; r < 4; ++r)
        mx[s][r] = fmaxf(mx[s][r], __shfl_xor(mx[s][r], off, 64));

  if (col == 0) {
    #pragma unroll
    for (int s = 0; s < NSUB; ++s)
      #pragma unroll
      for (int r = 0; r < 4; ++r) {
        const int tok = tokbase + s * 16 + q * 4 + r;
        splitmin[(size_t)tok * CSPLIT + split] = -mx[s][r];
      }
  }
}

// ---- exact pass: per token, fp32-scan qualifying splits (2 per iteration) ----
// Fuses refine + tokfin + one-hot scatter.
__global__ __launch_bounds__(256) void exact_kernel(const float* __restrict__ x,
                                                    const float4* __restrict__ cbT4,
                                                    const float4* __restrict__ c24,
                                                    const float* __restrict__ cb,
                                                    const float* __restrict__ splitmin,
                                                    float* __restrict__ disc,
                                                    float* __restrict__ quant,
                                                    float* __restrict__ counts,
                                                    float* __restrict__ sums) {
  const int wv = threadIdx.x >> 6;
  const int lane = threadIdx.x & 63;
  const int tok = __builtin_amdgcn_readfirstlane(blockIdx.x * 4 + wv);

  float4 xr[16];
  const float4* xp = (const float4*)(x + (size_t)tok * DD);
  #pragma unroll
  for (int i = 0; i < 16; ++i) xr[i] = xp[i];

  // gmin from splitmin (64 splits = 64 lanes, no global atomics anywhere)
  float sm = splitmin[(size_t)tok * CSPLIT + lane];
  float gmin = sm;
  #pragma unroll
  for (int off = 32; off; off >>= 1) gmin = fminf(gmin, __shfl_xor(gmin, off, 64));
  unsigned long long mask = __ballot(sm <= gmin + XMARGIN);

  float bs = 3.4e38f;
  int bc = 0x7FFFFFFF;

  while (mask) {
    const int s0 = __builtin_ctzll(mask); mask &= mask - 1;
    int s1 = s0;
    if (mask) { s1 = __builtin_ctzll(mask); mask &= mask - 1; }
    const int s = (lane < 32) ? s0 : s1;
    const int k4 = s * 32 + (lane & 31);   // 32 float4-groups x 4 codes = 128 codes
    float4 acc = {0.f, 0.f, 0.f, 0.f};
    #pragma unroll
    for (int d = 0; d < DD; ++d) {
      const float xd = ((const float*)xr)[d];
      const float4 cv = cbT4[(size_t)d * (KK / 4) + k4];
      acc.x = fmaf(xd, cv.x, acc.x);
      acc.y = fmaf(xd, cv.y, acc.y);
      acc.z = fmaf(xd, cv.z, acc.z);
      acc.w = fmaf(xd, cv.w, acc.w);
    }
    const float4 cc = c24[k4];
    const int cbase = k4 * 4;
    float sc;
    sc = fmaf(-2.f, acc.x, cc.x); if (sc < bs) { bs = sc; bc = cbase; }
    sc = fmaf(-2.f, acc.y, cc.y); if (sc < bs) { bs = sc; bc = cbase + 1; }
    sc = fmaf(-2.f, acc.z, cc.z); if (sc < bs) { bs = sc; bc = cbase + 2; }
    sc = fmaf(-2.f, acc.w, cc.w); if (sc < bs) { bs = sc; bc = cbase + 3; }
  }

  // 64-lane argmin reduce, lowest-index tie-break (matches jnp.argmin)
  #pragma unroll
  for (int off = 32; off; off >>= 1) {
    float os = __shfl_xor(bs, off, 64);
    int oc = __shfl_xor(bc, off, 64);
    if (os < bs || (os == bs && oc < bc)) { bs = os; bc = oc; }
  }

  const int code = __builtin_amdgcn_readfirstlane(bc);
  quant[(size_t)tok * DD + lane] = cb[(size_t)code * DD + lane];
  atomicAdd(&sums[(size_t)code * DD + lane], x[(size_t)tok * DD + lane]);
  if (lane == 0) {
    disc[(size_t)tok * KK + code] = 1.0f;   // memset already zeroed the row
    atomicAdd(&counts[code], 1.0f);
  }
}

// ---- EMA finalize ----
__global__ __launch_bounds__(256) void finalize_kernel(
    const float* __restrict__ ema_count, const float* __restrict__ ema_weight,
    const float* __restrict__ counts, const float* __restrict__ sums,
    float* __restrict__ out_count, float* __restrict__ out_weight,
    float* __restrict__ out_cb) {
  const int e4 = blockIdx.x * 256 + threadIdx.x;
  const int k = e4 >> 4;
  float nc = ema_count[k] * DECAYF + counts[k] * (1.f - DECAYF);
  nc = (nc + EPSF) / (BATCHF + (float)KK * EPSF) * BATCHF;
  const float4 ew = ((const float4*)ema_weight)[e4];
  const float4 s  = ((const float4*)sums)[e4];
  float4 nw;
  nw.x = ew.x * DECAYF + s.x * (1.f - DECAYF);
  nw.y = ew.y * DECAYF + s.y * (1.f - DECAYF);
  nw.z = ew.z * DECAYF + s.z * (1.f - DECAYF);
  nw.w = ew.w * DECAYF + s.w * (1.f - DECAYF);
  ((float4*)out_weight)[e4] = nw;
  float4 ncb = make_float4(nw.x / nc, nw.y / nc, nw.z / nc, nw.w / nc);
  ((float4*)out_cb)[e4] = ncb;
  if ((e4 & 15) == 0) out_count[k] = nc;
}

extern "C" void kernel_launch(void* const* d_in, const int* in_sizes, int n_in,
                              void* d_out, int out_size, void* d_ws, size_t ws_size,
                              hipStream_t stream) {
  const float* x  = (const float*)d_in[0];
  const float* cb = (const float*)d_in[1];
  const float* ema_count  = (const float*)d_in[2];
  const float* ema_weight = (const float*)d_in[3];

  float* out        = (float*)d_out;
  float* disc       = out;
  float* quant      = disc + (size_t)NN * KK;
  float* out_count  = quant + (size_t)NN * DD;
  float* out_weight = out_count + KK;
  float* out_cb     = out_weight + (size_t)KK * DD;

  float* ws = (float*)d_ws;
  float*    sums     = ws;                                   // 524288 f
  float*    counts   = sums + (size_t)KK * DD;               // 8192 f
  float*    c2       = counts + KK;                          // 8192 f
  float*    splitmin = c2 + KK;                              // N*64 f (4 MB)
  unsigned short* xb  = (unsigned short*)(splitmin + (size_t)NN * CSPLIT);  // 2 MB bf16
  unsigned short* cbb = xb + (size_t)NN * DD;                // 1 MB bf16
  float*    cbT      = (float*)(cbb + (size_t)KK * DD);      // 2 MB fp32 transposed

  hipMemsetAsync(disc, 0, (size_t)NN * KK * sizeof(float), stream);       // one-hot zeros
  hipMemsetAsync(sums, 0, (size_t)(KK * DD + KK) * sizeof(float), stream); // sums+counts

  conv_kernel<<<NN * DD / 4 / 256, 256, 0, stream>>>((const float4*)x, (uint2*)xb, NN * DD / 4);
  cbprep_kernel<<<KK / 256, 256, 0, stream>>>(cb, cbb, c2, cbT);
  pass1_kernel<<<(NN / 512) * CSPLIT, 256, 0, stream>>>(xb, (const float4*)cbb, c2, splitmin);
  exact_kernel<<<NN / 4, 256, 0, stream>>>(x, (const float4*)cbT, (const float4*)c2, cb,
                                           splitmin, disc, quant, counts, sums);
  finalize_kernel<<<KK * DD / 4 / 256, 256, 0, stream>>>(
      ema_count, ema_weight, counts, sums, out_count, out_weight, out_cb);
}